// Round 1
// baseline (327.590 us; speedup 1.0000x reference)
//
#include <hip/hip_runtime.h>
#include <cstdint>

#define D_MODEL 1024
#define NHEADS 16
#define DKH 64
#define SEQL 2048
#define NBATCH 2
#define NROWS (NBATCH * SEQL) /* 4096 */

typedef __bf16 bf16;
typedef __bf16 bf16x4 __attribute__((ext_vector_type(4)));
typedef __bf16 bf16x8 __attribute__((ext_vector_type(8)));
typedef float f32x4 __attribute__((ext_vector_type(4)));

static __device__ __forceinline__ f32x4 mfma16(bf16x8 a, bf16x8 b, f32x4 c) {
  return __builtin_amdgcn_mfma_f32_16x16x32_bf16(a, b, c, 0, 0, 0);
}

// ---------------------------------------------------------------------------
// fp32 -> bf16 conversion of x and the 4 weight matrices, float4-vectorized.
// total quads = 4096*1024/4 + 4*(1024*1024/4) = 1048576 + 4*262144 = 2097152
// ---------------------------------------------------------------------------
__global__ __launch_bounds__(256) void convert_kernel(
    const float* __restrict__ x, const float* __restrict__ wq,
    const float* __restrict__ wk, const float* __restrict__ wv,
    const float* __restrict__ wo, bf16* __restrict__ xb,
    bf16* __restrict__ wqb, bf16* __restrict__ wkb, bf16* __restrict__ wvb,
    bf16* __restrict__ wob) {
  int i4 = blockIdx.x * 256 + threadIdx.x;
  const float* src;
  bf16* dst;
  int off;
  if (i4 < (NROWS * D_MODEL / 4)) {
    src = x; dst = xb; off = i4;
  } else {
    int j = i4 - NROWS * D_MODEL / 4;
    int sel = j >> 18;            // 262144 quads per weight
    off = j & ((1 << 18) - 1);
    src = sel == 0 ? wq : sel == 1 ? wk : sel == 2 ? wv : wo;
    dst = sel == 0 ? wqb : sel == 1 ? wkb : sel == 2 ? wvb : wob;
  }
  float4 v = ((const float4*)src)[off];
  bf16x4 o;
  o[0] = (bf16)v.x; o[1] = (bf16)v.y; o[2] = (bf16)v.z; o[3] = (bf16)v.w;
  ((bf16x4*)dst)[off] = o;
}

// ---------------------------------------------------------------------------
// bt-GEMM: C[M,N] = sum_k A[m,k]*B[n,k], A row-major [M,K], B row-major [N,K].
// 128x128 tile, BK=32, 4 waves each computing 64x64 via 4x4 of 16x16x32 MFMA.
// LDS stride 56 bf16 (112B): b128 16B-aligned, frag reads 2-way (free).
// ---------------------------------------------------------------------------
template <typename OutT>
__device__ __forceinline__ void gemm_body(const bf16* __restrict__ A,
                                          const bf16* __restrict__ Bm,
                                          OutT* __restrict__ C, int M, int N,
                                          int K) {
  __shared__ bf16 As[128][56];
  __shared__ bf16 Bs[128][56];
  const int t = threadIdx.x;
  const int wave = t >> 6, lane = t & 63;
  const int quad = lane >> 4, l16 = lane & 15;
  const int wm = (wave >> 1) << 6, wn = (wave & 1) << 6;
  const int bm = blockIdx.x << 7, bn = blockIdx.y << 7;

  f32x4 acc[4][4];
  for (int i = 0; i < 4; i++)
    for (int j = 0; j < 4; j++)
      for (int r = 0; r < 4; r++) acc[i][j][r] = 0.0f;

  const int r0 = t >> 2;              // 0..63
  const int c0 = (t & 3) << 3;        // 0,8,16,24

  for (int k0 = 0; k0 < K; k0 += 32) {
    *(bf16x8*)&As[r0][c0]      = *(const bf16x8*)&A[(size_t)(bm + r0) * K + k0 + c0];
    *(bf16x8*)&As[r0 + 64][c0] = *(const bf16x8*)&A[(size_t)(bm + r0 + 64) * K + k0 + c0];
    *(bf16x8*)&Bs[r0][c0]      = *(const bf16x8*)&Bm[(size_t)(bn + r0) * K + k0 + c0];
    *(bf16x8*)&Bs[r0 + 64][c0] = *(const bf16x8*)&Bm[(size_t)(bn + r0 + 64) * K + k0 + c0];
    __syncthreads();
    bf16x8 af[4], bfr[4];
    for (int mt = 0; mt < 4; mt++)
      af[mt] = *(bf16x8*)&As[wm + mt * 16 + l16][quad * 8];
    for (int nt = 0; nt < 4; nt++)
      bfr[nt] = *(bf16x8*)&Bs[wn + nt * 16 + l16][quad * 8];
    for (int mt = 0; mt < 4; mt++)
      for (int nt = 0; nt < 4; nt++)
        acc[mt][nt] = mfma16(af[mt], bfr[nt], acc[mt][nt]);
    __syncthreads();
  }
  // C/D layout (verified m89/m91): col = lane&15, row = quad*4 + reg
  for (int mt = 0; mt < 4; mt++)
    for (int nt = 0; nt < 4; nt++)
      for (int r = 0; r < 4; r++) {
        int row = bm + wm + mt * 16 + quad * 4 + r;
        int col = bn + wn + nt * 16 + l16;
        C[(size_t)row * N + col] = (OutT)acc[mt][nt][r];
      }
}

__global__ __launch_bounds__(256) void qkv_gemm(
    const bf16* __restrict__ A, const bf16* __restrict__ B0,
    const bf16* __restrict__ B1, const bf16* __restrict__ B2,
    bf16* __restrict__ C0, bf16* __restrict__ C1, bf16* __restrict__ C2) {
  const bf16* Bm = blockIdx.z == 0 ? B0 : blockIdx.z == 1 ? B1 : B2;
  bf16* C = blockIdx.z == 0 ? C0 : blockIdx.z == 1 ? C1 : C2;
  gemm_body<bf16>(A, Bm, C, NROWS, D_MODEL, D_MODEL);
}

__global__ __launch_bounds__(256) void o_gemm(const bf16* __restrict__ A,
                                              const bf16* __restrict__ Bm,
                                              float* __restrict__ C) {
  gemm_body<float>(A, Bm, C, NROWS, D_MODEL, D_MODEL);
}

// ---------------------------------------------------------------------------
// RoPE in-place on Q and K ([4096,1024] bf16). One thread per (even,odd) pair.
// freqs[p] = 10000^(-p/32), angle = pos * freq  (matches reference fp32 math).
// ---------------------------------------------------------------------------
__global__ __launch_bounds__(256) void rope_kernel(bf16* __restrict__ Q,
                                                   bf16* __restrict__ Kb,
                                                   const int* __restrict__ tpos) {
  const int NP = NROWS * (D_MODEL / 2);  // 2097152 pairs per buffer
  int idx = blockIdx.x * 256 + threadIdx.x;
  bf16* buf = Q;
  int i = idx;
  if (idx >= NP) { buf = Kb; i = idx - NP; }
  int row = i >> 9;        // 512 pairs per row
  int wi = i & 511;
  int p = wi & 31;
  int col = (wi >> 5) * DKH + p * 2;
  int s = row & (SEQL - 1);
  float pos = (float)tpos[s];
  float freq = powf(10000.0f, -(float)p * (1.0f / 32.0f));
  float ang = pos * freq;
  float sn, cs;
  sincosf(ang, &sn, &cs);
  size_t o = (size_t)row * D_MODEL + col;
  float e = (float)buf[o], od = (float)buf[o + 1];
  buf[o]     = (bf16)(e * cs - od * sn);
  buf[o + 1] = (bf16)(e * sn + od * cs);
}

// ---------------------------------------------------------------------------
// Flash attention, causal. Block = (q-tile of 64) x (b,h). 4 waves, each wave
// owns 16 query rows. KV tiles of 64. 16x16x32 bf16 MFMA.
//   S = Q*K^T: A-frag = Q (A[m=lane&15][k=quad*8+j]), B-frag = K natural rows.
//   P -> LDS (bf16) -> reread as A-frag (verified transform, m118/m120/m122).
//   V transposed in LDS (Vt[d][key]) so B-frags are contiguous b128 reads.
// Online softmax state per row held redundantly across the quad's 16 lanes;
// row reductions via __shfl_xor 1,2,4,8 (stay within quad).
// ---------------------------------------------------------------------------
__global__ __launch_bounds__(256) void attn_kernel(const bf16* __restrict__ Q,
                                                   const bf16* __restrict__ K,
                                                   const bf16* __restrict__ V,
                                                   bf16* __restrict__ O) {
  const int t = threadIdx.x;
  const int wave = t >> 6, lane = t & 63;
  const int quad = lane >> 4, l16 = lane & 15;
  const int qt = blockIdx.x;                 // 0..31
  const int bh = blockIdx.y;                 // 0..31
  const int b = bh >> 4, h = bh & 15;
  const int q_base = qt * 64;
  const size_t base = (size_t)b * SEQL * D_MODEL + h * DKH;

  __shared__ bf16 Qs[64][72];
  __shared__ bf16 Ks[64][72];
  __shared__ bf16 Vs[64][66];   // stride 66 -> column reads 2-way (free)
  __shared__ bf16 Vt[64][72];   // [d][key]
  __shared__ bf16 Ps[4][16][72];

  // stage Q tile once (64 rows x 64 cols), 16B vector loads
  for (int i = 0; i < 2; i++) {
    int idx = t + i * 256;
    int row = idx >> 3, c8 = (idx & 7) * 8;
    *(bf16x8*)&Qs[row][c8] =
        *(const bf16x8*)&Q[base + (size_t)(q_base + row) * D_MODEL + c8];
  }
  __syncthreads();

  const int qrow = wave * 16 + l16;
  bf16x8 qa[2];
  qa[0] = *(bf16x8*)&Qs[qrow][quad * 8];
  qa[1] = *(bf16x8*)&Qs[qrow][32 + quad * 8];

  f32x4 oacc[4];
  for (int nt = 0; nt < 4; nt++)
    for (int r = 0; r < 4; r++) oacc[nt][r] = 0.0f;
  float m_i[4], l_i[4];
  for (int r = 0; r < 4; r++) { m_i[r] = -1e30f; l_i[r] = 0.0f; }

  const float scale = 0.125f;  // 1/sqrt(64)
  const int q_glob0 = q_base + wave * 16 + quad * 4;

  for (int kv = 0; kv <= qt; kv++) {
    const int kv_base = kv * 64;
    // ---- stage K (b128) and V (dword, into stride-66 Vs) ----
    for (int i = 0; i < 2; i++) {
      int idx = t + i * 256;
      int row = idx >> 3, c8 = (idx & 7) * 8;
      *(bf16x8*)&Ks[row][c8] =
          *(const bf16x8*)&K[base + (size_t)(kv_base + row) * D_MODEL + c8];
    }
    for (int i = 0; i < 8; i++) {
      int w = t + i * 256;                // 0..2047 dwords
      int key = w >> 5, dw = w & 31;
      unsigned int val = *(const unsigned int*)&V[base + (size_t)(kv_base + key) * D_MODEL + dw * 2];
      *(unsigned int*)&Vs[key][dw * 2] = val;
    }
    __syncthreads();

    // ---- transpose Vs -> Vt (conflict-analyzed: 2-way both sides) ----
    for (int i = 0; i < 16; i++) {
      int d = wave * 16 + i;
      Vt[d][lane] = Vs[lane][d];
    }

    // ---- S = Q*K^T for this wave's 16 rows x 64 keys ----
    f32x4 s_acc[4];
    for (int nt = 0; nt < 4; nt++) {
      for (int r = 0; r < 4; r++) s_acc[nt][r] = 0.0f;
      bf16x8 kb0 = *(bf16x8*)&Ks[nt * 16 + l16][quad * 8];
      bf16x8 kb1 = *(bf16x8*)&Ks[nt * 16 + l16][32 + quad * 8];
      s_acc[nt] = mfma16(qa[0], kb0, s_acc[nt]);
      s_acc[nt] = mfma16(qa[1], kb1, s_acc[nt]);
    }
    __syncthreads();  // Vt visible to all; all Ks/Vs reads complete

    // ---- scale + causal mask (only diagonal tile needs it) ----
    const bool diag = (kv == qt);
    for (int nt = 0; nt < 4; nt++)
      for (int r = 0; r < 4; r++) {
        float s = s_acc[nt][r] * scale;
        if (diag && (kv_base + nt * 16 + l16) > (q_glob0 + r)) s = -1e30f;
        s_acc[nt][r] = s;
      }

    // ---- online softmax ----
    float tmax[4];
    for (int r = 0; r < 4; r++) {
      tmax[r] = fmaxf(fmaxf(s_acc[0][r], s_acc[1][r]),
                      fmaxf(s_acc[2][r], s_acc[3][r]));
    }
    for (int off = 1; off < 16; off <<= 1)
      for (int r = 0; r < 4; r++)
        tmax[r] = fmaxf(tmax[r], __shfl_xor(tmax[r], off));
    float alpha[4], tsum[4];
    for (int r = 0; r < 4; r++) {
      float mn = fmaxf(m_i[r], tmax[r]);
      alpha[r] = __expf(m_i[r] - mn);
      m_i[r] = mn;
      tsum[r] = 0.0f;
    }
    for (int nt = 0; nt < 4; nt++)
      for (int r = 0; r < 4; r++) {
        float p = __expf(s_acc[nt][r] - m_i[r]);
        s_acc[nt][r] = p;
        tsum[r] += p;
      }
    for (int off = 1; off < 16; off <<= 1)
      for (int r = 0; r < 4; r++) tsum[r] += __shfl_xor(tsum[r], off);
    for (int r = 0; r < 4; r++) l_i[r] = l_i[r] * alpha[r] + tsum[r];
    for (int nt = 0; nt < 4; nt++)
      for (int r = 0; r < 4; r++) oacc[nt][r] *= alpha[r];

    // ---- P (C-layout) -> LDS ----
    for (int nt = 0; nt < 4; nt++)
      for (int r = 0; r < 4; r++)
        Ps[wave][quad * 4 + r][nt * 16 + l16] = (bf16)s_acc[nt][r];
    __syncthreads();  // order P write -> P read (also keeps barriers uniform)

    // ---- O += P * V ----
    bf16x8 pa0 = *(bf16x8*)&Ps[wave][l16][quad * 8];
    bf16x8 pa1 = *(bf16x8*)&Ps[wave][l16][32 + quad * 8];
    for (int nt = 0; nt < 4; nt++) {
      bf16x8 vb0 = *(bf16x8*)&Vt[nt * 16 + l16][quad * 8];
      bf16x8 vb1 = *(bf16x8*)&Vt[nt * 16 + l16][32 + quad * 8];
      oacc[nt] = mfma16(pa0, vb0, oacc[nt]);
      oacc[nt] = mfma16(pa1, vb1, oacc[nt]);
    }
  }

  // ---- normalize and write concat[b*S + s][h*64 + d] ----
  float inv[4];
  for (int r = 0; r < 4; r++) inv[r] = 1.0f / l_i[r];
  for (int nt = 0; nt < 4; nt++)
    for (int r = 0; r < 4; r++) {
      size_t row = q_base + wave * 16 + quad * 4 + r;
      O[base + row * D_MODEL + nt * 16 + l16] = (bf16)(oacc[nt][r] * inv[r]);
    }
}

// ---------------------------------------------------------------------------
extern "C" void kernel_launch(void* const* d_in, const int* in_sizes, int n_in,
                              void* d_out, int out_size, void* d_ws,
                              size_t ws_size, hipStream_t stream) {
  const float* x = (const float*)d_in[0];
  const float* wq = (const float*)d_in[1];
  const float* wk = (const float*)d_in[2];
  const float* wv = (const float*)d_in[3];
  const float* wo = (const float*)d_in[4];
  // d_in[5] = mask (tril, implemented analytically)
  const int* tpos = (const int*)d_in[6];
  float* out = (float*)d_out;

  char* p = (char*)d_ws;
  bf16* xb  = (bf16*)p; p += (size_t)NROWS * D_MODEL * 2;   // 8 MB
  bf16* wqb = (bf16*)p; p += (size_t)D_MODEL * D_MODEL * 2; // 2 MB
  bf16* wkb = (bf16*)p; p += (size_t)D_MODEL * D_MODEL * 2;
  bf16* wvb = (bf16*)p; p += (size_t)D_MODEL * D_MODEL * 2;
  bf16* wob = (bf16*)p; p += (size_t)D_MODEL * D_MODEL * 2;
  bf16* Qb  = (bf16*)p; p += (size_t)NROWS * D_MODEL * 2;
  bf16* Kb  = (bf16*)p; p += (size_t)NROWS * D_MODEL * 2;
  bf16* Vb  = (bf16*)p; p += (size_t)NROWS * D_MODEL * 2;
  bf16* Cc  = (bf16*)p; p += (size_t)NROWS * D_MODEL * 2;   // total 48 MB

  // 1) fp32 -> bf16
  convert_kernel<<<8192, 256, 0, stream>>>(x, wq, wk, wv, wo, xb, wqb, wkb,
                                           wvb, wob);
  // 2) Q,K,V projections (bt-GEMM, z selects weight)
  qkv_gemm<<<dim3(NROWS / 128, D_MODEL / 128, 3), 256, 0, stream>>>(
      xb, wqb, wkb, wvb, Qb, Kb, Vb);
  // 3) RoPE on Q and K
  rope_kernel<<<16384, 256, 0, stream>>>(Qb, Kb, tpos);
  // 4) causal flash attention -> concat
  attn_kernel<<<dim3(SEQL / 64, NBATCH * NHEADS), 256, 0, stream>>>(Qb, Kb, Vb,
                                                                    Cc);
  // 5) output projection (fp32 out)
  o_gemm<<<dim3(NROWS / 128, D_MODEL / 128), 256, 0, stream>>>(Cc, wob, out);
}

// Round 2
// 299.288 us; speedup vs baseline: 1.0946x; 1.0946x over previous
//
#include <hip/hip_runtime.h>
#include <cstdint>

#define D_MODEL 1024
#define NHEADS 16
#define DKH 64
#define SEQL 2048
#define NBATCH 2
#define NROWS (NBATCH * SEQL) /* 4096 */

typedef __bf16 bf16;
typedef __bf16 bf16x2 __attribute__((ext_vector_type(2)));
typedef __bf16 bf16x4 __attribute__((ext_vector_type(4)));
typedef __bf16 bf16x8 __attribute__((ext_vector_type(8)));
typedef float f32x4 __attribute__((ext_vector_type(4)));

static __device__ __forceinline__ f32x4 mfma16(bf16x8 a, bf16x8 b, f32x4 c) {
  return __builtin_amdgcn_mfma_f32_16x16x32_bf16(a, b, c, 0, 0, 0);
}

// ---------------------------------------------------------------------------
// fp32 -> bf16 conversion of x and the 4 weight matrices, float4-vectorized.
// ---------------------------------------------------------------------------
__global__ __launch_bounds__(256) void convert_kernel(
    const float* __restrict__ x, const float* __restrict__ wq,
    const float* __restrict__ wk, const float* __restrict__ wv,
    const float* __restrict__ wo, bf16* __restrict__ xb,
    bf16* __restrict__ wqb, bf16* __restrict__ wkb, bf16* __restrict__ wvb,
    bf16* __restrict__ wob) {
  int i4 = blockIdx.x * 256 + threadIdx.x;
  const float* src;
  bf16* dst;
  int off;
  if (i4 < (NROWS * D_MODEL / 4)) {
    src = x; dst = xb; off = i4;
  } else {
    int j = i4 - NROWS * D_MODEL / 4;
    int sel = j >> 18;            // 262144 quads per weight
    off = j & ((1 << 18) - 1);
    src = sel == 0 ? wq : sel == 1 ? wk : sel == 2 ? wv : wo;
    dst = sel == 0 ? wqb : sel == 1 ? wkb : sel == 2 ? wvb : wob;
  }
  float4 v = ((const float4*)src)[off];
  bf16x4 o;
  o[0] = (bf16)v.x; o[1] = (bf16)v.y; o[2] = (bf16)v.z; o[3] = (bf16)v.w;
  ((bf16x4*)dst)[off] = o;
}

// ---------------------------------------------------------------------------
// bt-GEMM: C[M,N] = sum_k A[m,k]*B[n,k]. 128x128 tile, BK=32 (unchanged R1).
// ---------------------------------------------------------------------------
template <typename OutT>
__device__ __forceinline__ void gemm_body(const bf16* __restrict__ A,
                                          const bf16* __restrict__ Bm,
                                          OutT* __restrict__ C, int M, int N,
                                          int K) {
  __shared__ bf16 As[128][56];
  __shared__ bf16 Bs[128][56];
  const int t = threadIdx.x;
  const int wave = t >> 6, lane = t & 63;
  const int quad = lane >> 4, l16 = lane & 15;
  const int wm = (wave >> 1) << 6, wn = (wave & 1) << 6;
  const int bm = blockIdx.x << 7, bn = blockIdx.y << 7;

  f32x4 acc[4][4];
  for (int i = 0; i < 4; i++)
    for (int j = 0; j < 4; j++)
      for (int r = 0; r < 4; r++) acc[i][j][r] = 0.0f;

  const int r0 = t >> 2;
  const int c0 = (t & 3) << 3;

  for (int k0 = 0; k0 < K; k0 += 32) {
    *(bf16x8*)&As[r0][c0]      = *(const bf16x8*)&A[(size_t)(bm + r0) * K + k0 + c0];
    *(bf16x8*)&As[r0 + 64][c0] = *(const bf16x8*)&A[(size_t)(bm + r0 + 64) * K + k0 + c0];
    *(bf16x8*)&Bs[r0][c0]      = *(const bf16x8*)&Bm[(size_t)(bn + r0) * K + k0 + c0];
    *(bf16x8*)&Bs[r0 + 64][c0] = *(const bf16x8*)&Bm[(size_t)(bn + r0 + 64) * K + k0 + c0];
    __syncthreads();
    bf16x8 af[4], bfr[4];
    for (int mt = 0; mt < 4; mt++)
      af[mt] = *(bf16x8*)&As[wm + mt * 16 + l16][quad * 8];
    for (int nt = 0; nt < 4; nt++)
      bfr[nt] = *(bf16x8*)&Bs[wn + nt * 16 + l16][quad * 8];
    for (int mt = 0; mt < 4; mt++)
      for (int nt = 0; nt < 4; nt++)
        acc[mt][nt] = mfma16(af[mt], bfr[nt], acc[mt][nt]);
    __syncthreads();
  }
  for (int mt = 0; mt < 4; mt++)
    for (int nt = 0; nt < 4; nt++)
      for (int r = 0; r < 4; r++) {
        int row = bm + wm + mt * 16 + quad * 4 + r;
        int col = bn + wn + nt * 16 + l16;
        C[(size_t)row * N + col] = (OutT)acc[mt][nt][r];
      }
}

__global__ __launch_bounds__(256) void qkv_gemm(
    const bf16* __restrict__ A, const bf16* __restrict__ B0,
    const bf16* __restrict__ B1, const bf16* __restrict__ B2,
    bf16* __restrict__ C0, bf16* __restrict__ C1, bf16* __restrict__ C2) {
  const bf16* Bm = blockIdx.z == 0 ? B0 : blockIdx.z == 1 ? B1 : B2;
  bf16* C = blockIdx.z == 0 ? C0 : blockIdx.z == 1 ? C1 : C2;
  gemm_body<bf16>(A, Bm, C, NROWS, D_MODEL, D_MODEL);
}

__global__ __launch_bounds__(256) void o_gemm(const bf16* __restrict__ A,
                                              const bf16* __restrict__ Bm,
                                              float* __restrict__ C) {
  gemm_body<float>(A, Bm, C, NROWS, D_MODEL, D_MODEL);
}

// ---------------------------------------------------------------------------
// RoPE in-place on Q and K. One thread per 4 pairs (one b128 load/store).
// ---------------------------------------------------------------------------
__global__ __launch_bounds__(256) void rope_kernel(bf16* __restrict__ Q,
                                                   bf16* __restrict__ Kb,
                                                   const int* __restrict__ tpos) {
  const int NG = NROWS * (D_MODEL / 8);  // 524288 groups per buffer
  int idx = blockIdx.x * 256 + threadIdx.x;
  bf16* buf = Q;
  int i = idx;
  if (idx >= NG) { buf = Kb; i = idx - NG; }
  int row = i >> 7;          // 128 groups per row
  int g = i & 127;
  int p0 = (g & 7) * 4;      // pair index within head (8 groups per head)
  int col = (g >> 3) * DKH + p0 * 2;
  int s = row & (SEQL - 1);
  float pos = (float)tpos[s];
  size_t o = (size_t)row * D_MODEL + col;
  bf16x8 v = *(bf16x8*)&buf[o];
  bf16x8 out;
  for (int j = 0; j < 4; j++) {
    float freq = exp2f((float)(p0 + j) * (-13.28771238f / 32.0f));
    float ang = pos * freq;
    float sn, cs;
    __sincosf(ang, &sn, &cs);
    float e = (float)v[2 * j], od = (float)v[2 * j + 1];
    out[2 * j]     = (bf16)(e * cs - od * sn);
    out[2 * j + 1] = (bf16)(e * sn + od * cs);
  }
  *(bf16x8*)&buf[o] = out;
}

// ---------------------------------------------------------------------------
// Flash attention, causal. Q-tile 128/block (wave owns 32 queries = 2 m-tiles),
// KV-tile 64. 32 MFMA per wave per kv-iter, 2 barriers per iter.
//  - V transposed at staging time (packed dword writes, 2-way banks = free)
//  - Ps aliases the dead Qs LDS; wave-private -> no barrier for P round trip
//  - qt dispatch reversed (longest blocks first) for causal load balance
// LDS: QP 18432 + Ks 9216 + Vt 9216 = 36864 B -> 4 blocks/CU by LDS.
// ---------------------------------------------------------------------------
__global__ __launch_bounds__(256) void attn_kernel(const bf16* __restrict__ Q,
                                                   const bf16* __restrict__ K,
                                                   const bf16* __restrict__ V,
                                                   bf16* __restrict__ O) {
  const int t = threadIdx.x;
  const int wave = t >> 6, lane = t & 63;
  const int quad = lane >> 4, l16 = lane & 15;
  const int qt = 15 - blockIdx.x;            // reversed: most work first
  const int bh = blockIdx.y;
  const int b = bh >> 4, h = bh & 15;
  const int q_base = qt * 128;
  const size_t base = (size_t)b * SEQL * D_MODEL + h * DKH;

  __shared__ bf16 QP[128 * 72];  // Q tile, later reused as per-wave P buffer
  __shared__ bf16 Ks[64][72];
  __shared__ bf16 Vt[64][72];    // [d][key]

  // stage Q tile (128 x 64), b128 coalesced
  for (int i = 0; i < 4; i++) {
    int idx = t + i * 256;
    int row = idx >> 3, c8 = (idx & 7) * 8;
    *(bf16x8*)&QP[row * 72 + c8] =
        *(const bf16x8*)&Q[base + (size_t)(q_base + row) * D_MODEL + c8];
  }
  __syncthreads();

  bf16x8 qa[2][2];
  for (int m = 0; m < 2; m++) {
    int row = wave * 32 + m * 16 + l16;
    qa[m][0] = *(bf16x8*)&QP[row * 72 + quad * 8];
    qa[m][1] = *(bf16x8*)&QP[row * 72 + 32 + quad * 8];
  }
  // NOTE: every wave's qa reads precede its arrival at the first in-loop
  // barrier, and P writes happen after that barrier -> no extra barrier.

  f32x4 oacc[2][4];
  float m_i[2][4], l_i[2][4];
  for (int m = 0; m < 2; m++)
    for (int r = 0; r < 4; r++) {
      m_i[m][r] = -1e30f;
      l_i[m][r] = 0.0f;
      for (int nt = 0; nt < 4; nt++) oacc[m][nt][r] = 0.0f;
    }

  const float sc = 0.125f * 1.44269504f;  // 1/sqrt(64) * log2(e)
  const int kv_iters = 2 * qt + 2;

  // V-transpose staging geometry (per thread, loop-invariant)
  const int dg = lane >> 5;        // 0..1
  const int kp = lane & 31;        // key pair
  const int d0 = wave * 16 + dg * 8;

  for (int kv = 0; kv < kv_iters; kv++) {
    const int kv_base = kv * 64;
    // ---- stage K rows (b128 coalesced) ----
    for (int i = 0; i < 2; i++) {
      int idx = t + i * 256;
      int row = idx >> 3, c8 = (idx & 7) * 8;
      *(bf16x8*)&Ks[row][c8] =
          *(const bf16x8*)&K[base + (size_t)(kv_base + row) * D_MODEL + c8];
    }
    // ---- stage V transposed: 2 keys x 8 d per thread, packed dword writes ----
    {
      const bf16* vsrc = &V[base + (size_t)(kv_base + 2 * kp) * D_MODEL + d0];
      bf16x8 g0 = *(const bf16x8*)vsrc;
      bf16x8 g1 = *(const bf16x8*)(vsrc + D_MODEL);
      for (int j = 0; j < 8; j++) {
        bf16x2 w2;
        w2[0] = g0[j];
        w2[1] = g1[j];
        *(bf16x2*)&Vt[d0 + j][2 * kp] = w2;
      }
    }
    __syncthreads();

    // ---- S = Q K^T : 16 MFMA ----
    f32x4 s[2][4];
    for (int m = 0; m < 2; m++)
      for (int nt = 0; nt < 4; nt++)
        for (int r = 0; r < 4; r++) s[m][nt][r] = 0.0f;
    for (int nt = 0; nt < 4; nt++) {
      bf16x8 kb0 = *(bf16x8*)&Ks[nt * 16 + l16][quad * 8];
      bf16x8 kb1 = *(bf16x8*)&Ks[nt * 16 + l16][32 + quad * 8];
      for (int m = 0; m < 2; m++) {
        s[m][nt] = mfma16(qa[m][0], kb0, s[m][nt]);
        s[m][nt] = mfma16(qa[m][1], kb1, s[m][nt]);
      }
    }

    // ---- scale (exp2 domain) + causal mask (only near-diagonal tiles) ----
    for (int m = 0; m < 2; m++) {
      for (int nt = 0; nt < 4; nt++)
        for (int r = 0; r < 4; r++) s[m][nt][r] *= sc;
      int q0m = q_base + wave * 32 + m * 16;   // wave-uniform
      if (kv_base + 63 > q0m) {
        int q0 = q0m + quad * 4;
        for (int nt = 0; nt < 4; nt++)
          for (int r = 0; r < 4; r++)
            if ((kv_base + nt * 16 + l16) > (q0 + r)) s[m][nt][r] = -1e30f;
      }
    }

    // ---- online softmax + P -> LDS (wave-private region of QP) ----
    for (int m = 0; m < 2; m++) {
      float tmax[4];
      for (int r = 0; r < 4; r++)
        tmax[r] = fmaxf(fmaxf(s[m][0][r], s[m][1][r]),
                        fmaxf(s[m][2][r], s[m][3][r]));
      for (int off = 1; off < 16; off <<= 1)
        for (int r = 0; r < 4; r++)
          tmax[r] = fmaxf(tmax[r], __shfl_xor(tmax[r], off));
      float alpha[4], tsum[4];
      for (int r = 0; r < 4; r++) {
        float mn = fmaxf(m_i[m][r], tmax[r]);
        alpha[r] = exp2f(m_i[m][r] - mn);
        m_i[m][r] = mn;
        tsum[r] = 0.0f;
      }
      for (int nt = 0; nt < 4; nt++)
        for (int r = 0; r < 4; r++) {
          float p = exp2f(s[m][nt][r] - m_i[m][r]);
          s[m][nt][r] = p;
          tsum[r] += p;
        }
      for (int off = 1; off < 16; off <<= 1)
        for (int r = 0; r < 4; r++) tsum[r] += __shfl_xor(tsum[r], off);
      for (int r = 0; r < 4; r++) l_i[m][r] = l_i[m][r] * alpha[r] + tsum[r];
      for (int nt = 0; nt < 4; nt++)
        for (int r = 0; r < 4; r++) oacc[m][nt][r] *= alpha[r];
      int prow = wave * 32 + m * 16 + quad * 4;
      for (int nt = 0; nt < 4; nt++)
        for (int r = 0; r < 4; r++)
          QP[(prow + r) * 72 + nt * 16 + l16] = (bf16)s[m][nt][r];
    }

    // ---- O += P V : 16 MFMA (P round trip is wave-private, no barrier) ----
    bf16x8 pa[2][2];
    for (int m = 0; m < 2; m++) {
      int row = wave * 32 + m * 16 + l16;
      pa[m][0] = *(bf16x8*)&QP[row * 72 + quad * 8];
      pa[m][1] = *(bf16x8*)&QP[row * 72 + 32 + quad * 8];
    }
    for (int nt = 0; nt < 4; nt++) {
      bf16x8 vb0 = *(bf16x8*)&Vt[nt * 16 + l16][quad * 8];
      bf16x8 vb1 = *(bf16x8*)&Vt[nt * 16 + l16][32 + quad * 8];
      for (int m = 0; m < 2; m++) {
        oacc[m][nt] = mfma16(pa[m][0], vb0, oacc[m][nt]);
        oacc[m][nt] = mfma16(pa[m][1], vb1, oacc[m][nt]);
      }
    }
    __syncthreads();  // Ks/Vt reads complete before next staging
  }

  // ---- normalize and write concat[b*S + s][h*64 + d] ----
  for (int m = 0; m < 2; m++) {
    float inv[4];
    for (int r = 0; r < 4; r++) inv[r] = 1.0f / l_i[m][r];
    for (int nt = 0; nt < 4; nt++)
      for (int r = 0; r < 4; r++) {
        size_t row = q_base + wave * 32 + m * 16 + quad * 4 + r;
        O[base + row * D_MODEL + nt * 16 + l16] = (bf16)(oacc[m][nt][r] * inv[r]);
      }
  }
}

// ---------------------------------------------------------------------------
extern "C" void kernel_launch(void* const* d_in, const int* in_sizes, int n_in,
                              void* d_out, int out_size, void* d_ws,
                              size_t ws_size, hipStream_t stream) {
  const float* x = (const float*)d_in[0];
  const float* wq = (const float*)d_in[1];
  const float* wk = (const float*)d_in[2];
  const float* wv = (const float*)d_in[3];
  const float* wo = (const float*)d_in[4];
  const int* tpos = (const int*)d_in[6];
  float* out = (float*)d_out;

  char* p = (char*)d_ws;
  bf16* xb  = (bf16*)p; p += (size_t)NROWS * D_MODEL * 2;
  bf16* wqb = (bf16*)p; p += (size_t)D_MODEL * D_MODEL * 2;
  bf16* wkb = (bf16*)p; p += (size_t)D_MODEL * D_MODEL * 2;
  bf16* wvb = (bf16*)p; p += (size_t)D_MODEL * D_MODEL * 2;
  bf16* wob = (bf16*)p; p += (size_t)D_MODEL * D_MODEL * 2;
  bf16* Qb  = (bf16*)p; p += (size_t)NROWS * D_MODEL * 2;
  bf16* Kb  = (bf16*)p; p += (size_t)NROWS * D_MODEL * 2;
  bf16* Vb  = (bf16*)p; p += (size_t)NROWS * D_MODEL * 2;
  bf16* Cc  = (bf16*)p; p += (size_t)NROWS * D_MODEL * 2;

  convert_kernel<<<8192, 256, 0, stream>>>(x, wq, wk, wv, wo, xb, wqb, wkb,
                                           wvb, wob);
  qkv_gemm<<<dim3(NROWS / 128, D_MODEL / 128, 3), 256, 0, stream>>>(
      xb, wqb, wkb, wvb, Qb, Kb, Vb);
  rope_kernel<<<4096, 256, 0, stream>>>(Qb, Kb, tpos);
  attn_kernel<<<dim3(SEQL / 128, NBATCH * NHEADS), 256, 0, stream>>>(Qb, Kb,
                                                                     Vb, Cc);
  o_gemm<<<dim3(NROWS / 128, D_MODEL / 128), 256, 0, stream>>>(Cc, wob, out);
}

// Round 3
// 289.859 us; speedup vs baseline: 1.1302x; 1.0325x over previous
//
#include <hip/hip_runtime.h>
#include <cstdint>

#define D_MODEL 1024
#define NHEADS 16
#define DKH 64
#define SEQL 2048
#define NBATCH 2
#define NROWS (NBATCH * SEQL) /* 4096 */

typedef __bf16 bf16;
typedef __bf16 bf16x2 __attribute__((ext_vector_type(2)));
typedef __bf16 bf16x4 __attribute__((ext_vector_type(4)));
typedef __bf16 bf16x8 __attribute__((ext_vector_type(8)));
typedef float f32x4 __attribute__((ext_vector_type(4)));

static __device__ __forceinline__ f32x4 mfma16(bf16x8 a, bf16x8 b, f32x4 c) {
  return __builtin_amdgcn_mfma_f32_16x16x32_bf16(a, b, c, 0, 0, 0);
}

// async global->LDS, 16B per lane (emits global_load_lds_dwordx4).
// LDS dest must be wave-uniform base; HW scatters lane*16.
static __device__ __forceinline__ void gload_lds16(const bf16* g, bf16* l) {
  __builtin_amdgcn_global_load_lds(
      (const __attribute__((address_space(1))) void*)g,
      (__attribute__((address_space(3))) void*)l, 16, 0, 0);
}

// ---------------------------------------------------------------------------
// fp32 -> bf16 conversion of x and the 4 weight matrices, float4-vectorized.
// ---------------------------------------------------------------------------
__global__ __launch_bounds__(256) void convert_kernel(
    const float* __restrict__ x, const float* __restrict__ wq,
    const float* __restrict__ wk, const float* __restrict__ wv,
    const float* __restrict__ wo, bf16* __restrict__ xb,
    bf16* __restrict__ wqb, bf16* __restrict__ wkb, bf16* __restrict__ wvb,
    bf16* __restrict__ wob) {
  int i4 = blockIdx.x * 256 + threadIdx.x;
  const float* src;
  bf16* dst;
  int off;
  if (i4 < (NROWS * D_MODEL / 4)) {
    src = x; dst = xb; off = i4;
  } else {
    int j = i4 - NROWS * D_MODEL / 4;
    int sel = j >> 18;
    off = j & ((1 << 18) - 1);
    src = sel == 0 ? wq : sel == 1 ? wk : sel == 2 ? wv : wo;
    dst = sel == 0 ? wqb : sel == 1 ? wkb : sel == 2 ? wvb : wob;
  }
  float4 v = ((const float4*)src)[off];
  bf16x4 o;
  o[0] = (bf16)v.x; o[1] = (bf16)v.y; o[2] = (bf16)v.z; o[3] = (bf16)v.w;
  ((bf16x4*)dst)[off] = o;
}

// ---------------------------------------------------------------------------
// bt-GEMM, m97 structure: 128x128 tile, BK=32, unpadded LDS [128][32],
// global_load_lds width=16 staging (contiguous lane order), 2 barriers/iter.
// ---------------------------------------------------------------------------
template <typename OutT>
__device__ __forceinline__ void gemm_body(const bf16* __restrict__ A,
                                          const bf16* __restrict__ Bm,
                                          OutT* __restrict__ C, int M, int N,
                                          int K) {
  __shared__ bf16 As[128 * 32];
  __shared__ bf16 Bs[128 * 32];
  const int t = threadIdx.x;
  const int wave = t >> 6, lane = t & 63;
  const int quad = lane >> 4, l16 = lane & 15;
  const int wm = (wave >> 1) << 6, wn = (wave & 1) << 6;
  const int bm = blockIdx.x << 7, bn = blockIdx.y << 7;

  f32x4 acc[4][4];
  for (int i = 0; i < 4; i++)
    for (int j = 0; j < 4; j++)
      for (int r = 0; r < 4; r++) acc[i][j][r] = 0.0f;

  // chunk c (16B) <-> row = c>>2, col = (c&3)*8; wave w instr j covers chunks
  // [(w*2+j)*64, +64), lane l -> chunk base+l. LDS base wave-uniform.
  int ca = (wave * 2) * 64 + lane;      // chunk for j=0
  int cb = ca + 64;                     // chunk for j=1
  const int ra0 = ca >> 2, ca0 = (ca & 3) * 8;
  const int rb0 = cb >> 2, cb0 = (cb & 3) * 8;
  bf16* ldsA0 = &As[(wave * 2 + 0) * 512];
  bf16* ldsA1 = &As[(wave * 2 + 1) * 512];
  bf16* ldsB0 = &Bs[(wave * 2 + 0) * 512];
  bf16* ldsB1 = &Bs[(wave * 2 + 1) * 512];

  for (int k0 = 0; k0 < K; k0 += 32) {
    gload_lds16(&A[(size_t)(bm + ra0) * K + k0 + ca0], ldsA0);
    gload_lds16(&A[(size_t)(bm + rb0) * K + k0 + cb0], ldsA1);
    gload_lds16(&Bm[(size_t)(bn + ra0) * K + k0 + ca0], ldsB0);
    gload_lds16(&Bm[(size_t)(bn + rb0) * K + k0 + cb0], ldsB1);
    __syncthreads();
    bf16x8 af[4], bfr[4];
    for (int mt = 0; mt < 4; mt++)
      af[mt] = *(bf16x8*)&As[(wm + mt * 16 + l16) * 32 + quad * 8];
    for (int nt = 0; nt < 4; nt++)
      bfr[nt] = *(bf16x8*)&Bs[(wn + nt * 16 + l16) * 32 + quad * 8];
    for (int mt = 0; mt < 4; mt++)
      for (int nt = 0; nt < 4; nt++)
        acc[mt][nt] = mfma16(af[mt], bfr[nt], acc[mt][nt]);
    __syncthreads();
  }
  for (int mt = 0; mt < 4; mt++)
    for (int nt = 0; nt < 4; nt++)
      for (int r = 0; r < 4; r++) {
        int row = bm + wm + mt * 16 + quad * 4 + r;
        int col = bn + wn + nt * 16 + l16;
        C[(size_t)row * N + col] = (OutT)acc[mt][nt][r];
      }
}

__global__ __launch_bounds__(256) void qkv_gemm(
    const bf16* __restrict__ A, const bf16* __restrict__ B0,
    const bf16* __restrict__ B1, const bf16* __restrict__ B2,
    bf16* __restrict__ C0, bf16* __restrict__ C1, bf16* __restrict__ C2) {
  const bf16* Bm = blockIdx.z == 0 ? B0 : blockIdx.z == 1 ? B1 : B2;
  bf16* C = blockIdx.z == 0 ? C0 : blockIdx.z == 1 ? C1 : C2;
  gemm_body<bf16>(A, Bm, C, NROWS, D_MODEL, D_MODEL);
}

__global__ __launch_bounds__(256) void o_gemm(const bf16* __restrict__ A,
                                              const bf16* __restrict__ Bm,
                                              float* __restrict__ C) {
  gemm_body<float>(A, Bm, C, NROWS, D_MODEL, D_MODEL);
}

// ---------------------------------------------------------------------------
// RoPE in-place on Q and K. One thread per 4 pairs. Q is additionally
// pre-scaled by 0.125*log2(e) so attention scores land in exp2 domain free.
// ---------------------------------------------------------------------------
__global__ __launch_bounds__(256) void rope_kernel(bf16* __restrict__ Q,
                                                   bf16* __restrict__ Kb,
                                                   const int* __restrict__ tpos) {
  const int NG = NROWS * (D_MODEL / 8);
  int idx = blockIdx.x * 256 + threadIdx.x;
  bf16* buf = Q;
  int i = idx;
  float qsc = 0.125f * 1.44269504f;
  if (idx >= NG) { buf = Kb; i = idx - NG; qsc = 1.0f; }
  int row = i >> 7;
  int g = i & 127;
  int p0 = (g & 7) * 4;
  int col = (g >> 3) * DKH + p0 * 2;
  int s = row & (SEQL - 1);
  float pos = (float)tpos[s];
  size_t o = (size_t)row * D_MODEL + col;
  bf16x8 v = *(bf16x8*)&buf[o];
  bf16x8 out;
  for (int j = 0; j < 4; j++) {
    float freq = exp2f((float)(p0 + j) * (-13.28771238f / 32.0f));
    float ang = pos * freq;
    float sn, cs;
    __sincosf(ang, &sn, &cs);
    cs *= qsc; sn *= qsc;
    float e = (float)v[2 * j], od = (float)v[2 * j + 1];
    out[2 * j]     = (bf16)(e * cs - od * sn);
    out[2 * j + 1] = (bf16)(e * sn + od * cs);
  }
  *(bf16x8*)&buf[o] = out;
}

// ---------------------------------------------------------------------------
// Flash attention, causal. Q-tile 128, KV-tile 128. 64 MFMA/wave/iter,
// 2 barriers/iter. qt+1 iters per block.
//  - grid 512 1D with complementary pairing: block k and k+256 get qt and
//    15-qt -> each CU's pair sums to 34 iters (load balance; R2 showed
//    same-qt pairing => makespan = 64-iter critical path, occupancy 11%).
//  - Q pre-scaled (rope) => no per-element scale; exp2-domain softmax.
//  - l-sum deferred: per-lane partials, single shfl-reduce at end.
//  - P routed through wave-private QP slice in two 64-key halves.
// LDS: QP 18432 + Ks 18432 + Vt 17408 = 54272 B -> 2 blocks/CU.
// ---------------------------------------------------------------------------
__global__ __launch_bounds__(256) void attn_kernel(const bf16* __restrict__ Q,
                                                   const bf16* __restrict__ K,
                                                   const bf16* __restrict__ V,
                                                   bf16* __restrict__ O) {
  const int t = threadIdx.x;
  const int wave = t >> 6, lane = t & 63;
  const int quad = lane >> 4, l16 = lane & 15;
  const int id = blockIdx.x;
  const int half = id >> 8, rr = id & 255;
  const int qt = half ? 15 - (rr & 15) : (rr & 15);
  const int bh = (half << 4) | (rr >> 4);
  const int b = bh >> 4, h = bh & 15;
  const int q_base = qt * 128;
  const size_t base = (size_t)b * SEQL * D_MODEL + h * DKH;

  __shared__ bf16 QP[128 * 72];   // Q tile; per-wave P buffer after qa loads
  __shared__ bf16 Ks[128 * 72];
  __shared__ bf16 Vt[64 * 136];   // [d][key], key 0..127

  // stage Q tile (128 x 64), b128 coalesced
  for (int i = 0; i < 4; i++) {
    int idx = t + i * 256;
    int row = idx >> 3, c8 = (idx & 7) * 8;
    *(bf16x8*)&QP[row * 72 + c8] =
        *(const bf16x8*)&Q[base + (size_t)(q_base + row) * D_MODEL + c8];
  }
  __syncthreads();

  bf16x8 qa[2][2];
  for (int m = 0; m < 2; m++) {
    int row = wave * 32 + m * 16 + l16;
    qa[m][0] = *(bf16x8*)&QP[row * 72 + quad * 8];
    qa[m][1] = *(bf16x8*)&QP[row * 72 + 32 + quad * 8];
  }

  f32x4 oacc[2][4];
  float m_i[2][4], l_lane[2][4];
  for (int m = 0; m < 2; m++)
    for (int r = 0; r < 4; r++) {
      m_i[m][r] = -1e30f;
      l_lane[m][r] = 0.0f;
      for (int dt = 0; dt < 4; dt++) oacc[m][dt][r] = 0.0f;
    }

  // V-transpose staging geometry
  // task u = t + i*256 (i<2): key-pair kp = u&63, d-group d0 = (u>>6)*8
  const int kp = t & 63;
  const int dgbase = t >> 6;  // wave: dg = dgbase + 4*i

  for (int kv = 0; kv <= qt; kv++) {
    const int kv_base = kv * 128;
    // ---- stage K rows (128 x 64, b128 coalesced) ----
    for (int i = 0; i < 4; i++) {
      int idx = t + i * 256;
      int row = idx >> 3, c8 = (idx & 7) * 8;
      *(bf16x8*)&Ks[row * 72 + c8] =
          *(const bf16x8*)&K[base + (size_t)(kv_base + row) * D_MODEL + c8];
    }
    // ---- stage V transposed: Vt[d][key] ----
    for (int i = 0; i < 2; i++) {
      int d0 = (dgbase + 4 * i) * 8;
      const bf16* vsrc = &V[base + (size_t)(kv_base + 2 * kp) * D_MODEL + d0];
      bf16x8 g0 = *(const bf16x8*)vsrc;
      bf16x8 g1 = *(const bf16x8*)(vsrc + D_MODEL);
      for (int j = 0; j < 8; j++) {
        bf16x2 w2;
        w2[0] = g0[j];
        w2[1] = g1[j];
        *(bf16x2*)&Vt[(d0 + j) * 136 + 2 * kp] = w2;
      }
    }
    __syncthreads();

    // ---- S = Q K^T : 32 MFMA (2m x 8nt x 2k) ----
    f32x4 s[2][8];
    for (int m = 0; m < 2; m++)
      for (int nt = 0; nt < 8; nt++)
        for (int r = 0; r < 4; r++) s[m][nt][r] = 0.0f;
    for (int nt = 0; nt < 8; nt++) {
      bf16x8 kb0 = *(bf16x8*)&Ks[(nt * 16 + l16) * 72 + quad * 8];
      bf16x8 kb1 = *(bf16x8*)&Ks[(nt * 16 + l16) * 72 + 32 + quad * 8];
      for (int m = 0; m < 2; m++) {
        s[m][nt] = mfma16(qa[m][0], kb0, s[m][nt]);
        s[m][nt] = mfma16(qa[m][1], kb1, s[m][nt]);
      }
    }

    // ---- causal mask (diagonal super-tile only; block-local indices) ----
    if (kv == qt) {
      for (int m = 0; m < 2; m++) {
        int q0 = wave * 32 + m * 16 + quad * 4;
        for (int nt = 0; nt < 8; nt++) {
          int kc = nt * 16 + l16;
          for (int r = 0; r < 4; r++)
            if (kc > q0 + r) s[m][nt][r] = -1e30f;
        }
      }
    }

    // ---- online softmax (log2 domain; l kept as per-lane partials) ----
    for (int m = 0; m < 2; m++) {
      float tmax[4];
      for (int r = 0; r < 4; r++) {
        float a0 = fmaxf(fmaxf(s[m][0][r], s[m][1][r]),
                         fmaxf(s[m][2][r], s[m][3][r]));
        float a1 = fmaxf(fmaxf(s[m][4][r], s[m][5][r]),
                         fmaxf(s[m][6][r], s[m][7][r]));
        tmax[r] = fmaxf(a0, a1);
      }
      for (int off = 1; off < 16; off <<= 1)
        for (int r = 0; r < 4; r++)
          tmax[r] = fmaxf(tmax[r], __shfl_xor(tmax[r], off));
      float alpha[4];
      for (int r = 0; r < 4; r++) {
        float mn = fmaxf(m_i[m][r], tmax[r]);
        alpha[r] = exp2f(m_i[m][r] - mn);
        m_i[m][r] = mn;
      }
      float tsum[4] = {0.f, 0.f, 0.f, 0.f};
      for (int nt = 0; nt < 8; nt++)
        for (int r = 0; r < 4; r++) {
          float p = exp2f(s[m][nt][r] - m_i[m][r]);
          s[m][nt][r] = p;
          tsum[r] += p;
        }
      for (int r = 0; r < 4; r++)
        l_lane[m][r] = l_lane[m][r] * alpha[r] + tsum[r];
      for (int dt = 0; dt < 4; dt++)
        for (int r = 0; r < 4; r++) oacc[m][dt][r] *= alpha[r];
    }

    // ---- PV in two 64-key halves through wave-private QP slice ----
    for (int hf = 0; hf < 2; hf++) {
      for (int m = 0; m < 2; m++) {
        int prow = wave * 32 + m * 16 + quad * 4;
        for (int nt = 0; nt < 4; nt++)
          for (int r = 0; r < 4; r++)
            QP[(prow + r) * 72 + nt * 16 + l16] = (bf16)s[m][hf * 4 + nt][r];
      }
      // wave-private round trip: no barrier needed
      bf16x8 pa[2][2];
      for (int m = 0; m < 2; m++) {
        int row = wave * 32 + m * 16 + l16;
        pa[m][0] = *(bf16x8*)&QP[row * 72 + quad * 8];
        pa[m][1] = *(bf16x8*)&QP[row * 72 + 32 + quad * 8];
      }
      for (int dt = 0; dt < 4; dt++) {
        bf16x8 vb0 = *(bf16x8*)&Vt[(dt * 16 + l16) * 136 + hf * 64 + quad * 8];
        bf16x8 vb1 =
            *(bf16x8*)&Vt[(dt * 16 + l16) * 136 + hf * 64 + 32 + quad * 8];
        for (int m = 0; m < 2; m++) {
          oacc[m][dt] = mfma16(pa[m][0], vb0, oacc[m][dt]);
          oacc[m][dt] = mfma16(pa[m][1], vb1, oacc[m][dt]);
        }
      }
    }
    __syncthreads();  // all Ks/Vt/QP reads done before next staging
  }

  // ---- final l reduce across the 16 column-lanes, then write ----
  float l_full[2][4];
  for (int m = 0; m < 2; m++)
    for (int r = 0; r < 4; r++) l_full[m][r] = l_lane[m][r];
  for (int off = 1; off < 16; off <<= 1)
    for (int m = 0; m < 2; m++)
      for (int r = 0; r < 4; r++)
        l_full[m][r] += __shfl_xor(l_full[m][r], off);

  for (int m = 0; m < 2; m++) {
    float inv[4];
    for (int r = 0; r < 4; r++) inv[r] = 1.0f / l_full[m][r];
    for (int dt = 0; dt < 4; dt++)
      for (int r = 0; r < 4; r++) {
        size_t row = q_base + wave * 32 + m * 16 + quad * 4 + r;
        O[base + row * D_MODEL + dt * 16 + l16] =
            (bf16)(oacc[m][dt][r] * inv[r]);
      }
  }
}

// ---------------------------------------------------------------------------
extern "C" void kernel_launch(void* const* d_in, const int* in_sizes, int n_in,
                              void* d_out, int out_size, void* d_ws,
                              size_t ws_size, hipStream_t stream) {
  const float* x = (const float*)d_in[0];
  const float* wq = (const float*)d_in[1];
  const float* wk = (const float*)d_in[2];
  const float* wv = (const float*)d_in[3];
  const float* wo = (const float*)d_in[4];
  const int* tpos = (const int*)d_in[6];
  float* out = (float*)d_out;

  char* p = (char*)d_ws;
  bf16* xb  = (bf16*)p; p += (size_t)NROWS * D_MODEL * 2;
  bf16* wqb = (bf16*)p; p += (size_t)D_MODEL * D_MODEL * 2;
  bf16* wkb = (bf16*)p; p += (size_t)D_MODEL * D_MODEL * 2;
  bf16* wvb = (bf16*)p; p += (size_t)D_MODEL * D_MODEL * 2;
  bf16* wob = (bf16*)p; p += (size_t)D_MODEL * D_MODEL * 2;
  bf16* Qb  = (bf16*)p; p += (size_t)NROWS * D_MODEL * 2;
  bf16* Kb  = (bf16*)p; p += (size_t)NROWS * D_MODEL * 2;
  bf16* Vb  = (bf16*)p; p += (size_t)NROWS * D_MODEL * 2;
  bf16* Cc  = (bf16*)p; p += (size_t)NROWS * D_MODEL * 2;

  convert_kernel<<<8192, 256, 0, stream>>>(x, wq, wk, wv, wo, xb, wqb, wkb,
                                           wvb, wob);
  qkv_gemm<<<dim3(NROWS / 128, D_MODEL / 128, 3), 256, 0, stream>>>(
      xb, wqb, wkb, wvb, Qb, Kb, Vb);
  rope_kernel<<<4096, 256, 0, stream>>>(Qb, Kb, tpos);
  attn_kernel<<<512, 256, 0, stream>>>(Qb, Kb, Vb, Cc);
  o_gemm<<<dim3(NROWS / 128, D_MODEL / 128), 256, 0, stream>>>(Cc, wob, out);
}

// Round 4
// 243.759 us; speedup vs baseline: 1.3439x; 1.1891x over previous
//
#include <hip/hip_runtime.h>
#include <cstdint>

#define D_MODEL 1024
#define NHEADS 16
#define DKH 64
#define SEQL 2048
#define NBATCH 2
#define NROWS (NBATCH * SEQL) /* 4096 */

typedef __bf16 bf16;
typedef __bf16 bf16x2 __attribute__((ext_vector_type(2)));
typedef __bf16 bf16x4 __attribute__((ext_vector_type(4)));
typedef __bf16 bf16x8 __attribute__((ext_vector_type(8)));
typedef float f32x4 __attribute__((ext_vector_type(4)));

static __device__ __forceinline__ f32x4 mfma16(bf16x8 a, bf16x8 b, f32x4 c) {
  return __builtin_amdgcn_mfma_f32_16x16x32_bf16(a, b, c, 0, 0, 0);
}

static __device__ __forceinline__ void gload_lds16(const bf16* g, bf16* l) {
  __builtin_amdgcn_global_load_lds(
      (const __attribute__((address_space(1))) void*)g,
      (__attribute__((address_space(3))) void*)l, 16, 0, 0);
}

// ---------------------------------------------------------------------------
// fp32 -> bf16 conversion of x and the 4 weight matrices.
// ---------------------------------------------------------------------------
__global__ __launch_bounds__(256) void convert_kernel(
    const float* __restrict__ x, const float* __restrict__ wq,
    const float* __restrict__ wk, const float* __restrict__ wv,
    const float* __restrict__ wo, bf16* __restrict__ xb,
    bf16* __restrict__ wqb, bf16* __restrict__ wkb, bf16* __restrict__ wvb,
    bf16* __restrict__ wob) {
  int i4 = blockIdx.x * 256 + threadIdx.x;
  const float* src;
  bf16* dst;
  int off;
  if (i4 < (NROWS * D_MODEL / 4)) {
    src = x; dst = xb; off = i4;
  } else {
    int j = i4 - NROWS * D_MODEL / 4;
    int sel = j >> 18;
    off = j & ((1 << 18) - 1);
    src = sel == 0 ? wq : sel == 1 ? wk : sel == 2 ? wv : wo;
    dst = sel == 0 ? wqb : sel == 1 ? wkb : sel == 2 ? wvb : wob;
  }
  float4 v = ((const float4*)src)[off];
  bf16x4 o;
  o[0] = (bf16)v.x; o[1] = (bf16)v.y; o[2] = (bf16)v.z; o[3] = (bf16)v.w;
  ((bf16x4*)dst)[off] = o;
}

// ---------------------------------------------------------------------------
// bt-GEMM, m97 structure (unchanged from R3).
// ---------------------------------------------------------------------------
template <typename OutT>
__device__ __forceinline__ void gemm_body(const bf16* __restrict__ A,
                                          const bf16* __restrict__ Bm,
                                          OutT* __restrict__ C, int M, int N,
                                          int K) {
  __shared__ bf16 As[128 * 32];
  __shared__ bf16 Bs[128 * 32];
  const int t = threadIdx.x;
  const int wave = t >> 6, lane = t & 63;
  const int quad = lane >> 4, l16 = lane & 15;
  const int wm = (wave >> 1) << 6, wn = (wave & 1) << 6;
  const int bm = blockIdx.x << 7, bn = blockIdx.y << 7;

  f32x4 acc[4][4];
  for (int i = 0; i < 4; i++)
    for (int j = 0; j < 4; j++)
      for (int r = 0; r < 4; r++) acc[i][j][r] = 0.0f;

  int ca = (wave * 2) * 64 + lane;
  int cb = ca + 64;
  const int ra0 = ca >> 2, ca0 = (ca & 3) * 8;
  const int rb0 = cb >> 2, cb0 = (cb & 3) * 8;
  bf16* ldsA0 = &As[(wave * 2 + 0) * 512];
  bf16* ldsA1 = &As[(wave * 2 + 1) * 512];
  bf16* ldsB0 = &Bs[(wave * 2 + 0) * 512];
  bf16* ldsB1 = &Bs[(wave * 2 + 1) * 512];

  for (int k0 = 0; k0 < K; k0 += 32) {
    gload_lds16(&A[(size_t)(bm + ra0) * K + k0 + ca0], ldsA0);
    gload_lds16(&A[(size_t)(bm + rb0) * K + k0 + cb0], ldsA1);
    gload_lds16(&Bm[(size_t)(bn + ra0) * K + k0 + ca0], ldsB0);
    gload_lds16(&Bm[(size_t)(bn + rb0) * K + k0 + cb0], ldsB1);
    __syncthreads();
    bf16x8 af[4], bfr[4];
    for (int mt = 0; mt < 4; mt++)
      af[mt] = *(bf16x8*)&As[(wm + mt * 16 + l16) * 32 + quad * 8];
    for (int nt = 0; nt < 4; nt++)
      bfr[nt] = *(bf16x8*)&Bs[(wn + nt * 16 + l16) * 32 + quad * 8];
    for (int mt = 0; mt < 4; mt++)
      for (int nt = 0; nt < 4; nt++)
        acc[mt][nt] = mfma16(af[mt], bfr[nt], acc[mt][nt]);
    __syncthreads();
  }
  for (int mt = 0; mt < 4; mt++)
    for (int nt = 0; nt < 4; nt++)
      for (int r = 0; r < 4; r++) {
        int row = bm + wm + mt * 16 + quad * 4 + r;
        int col = bn + wn + nt * 16 + l16;
        C[(size_t)row * N + col] = (OutT)acc[mt][nt][r];
      }
}

__global__ __launch_bounds__(256) void qkv_gemm(
    const bf16* __restrict__ A, const bf16* __restrict__ B0,
    const bf16* __restrict__ B1, const bf16* __restrict__ B2,
    bf16* __restrict__ C0, bf16* __restrict__ C1, bf16* __restrict__ C2) {
  const bf16* Bm = blockIdx.z == 0 ? B0 : blockIdx.z == 1 ? B1 : B2;
  bf16* C = blockIdx.z == 0 ? C0 : blockIdx.z == 1 ? C1 : C2;
  gemm_body<bf16>(A, Bm, C, NROWS, D_MODEL, D_MODEL);
}

__global__ __launch_bounds__(256) void o_gemm(const bf16* __restrict__ A,
                                              const bf16* __restrict__ Bm,
                                              float* __restrict__ C) {
  gemm_body<float>(A, Bm, C, NROWS, D_MODEL, D_MODEL);
}

// ---------------------------------------------------------------------------
// RoPE in-place; Q additionally pre-scaled by 0.125*log2(e).
// ---------------------------------------------------------------------------
__global__ __launch_bounds__(256) void rope_kernel(bf16* __restrict__ Q,
                                                   bf16* __restrict__ Kb,
                                                   const int* __restrict__ tpos) {
  const int NG = NROWS * (D_MODEL / 8);
  int idx = blockIdx.x * 256 + threadIdx.x;
  bf16* buf = Q;
  int i = idx;
  float qsc = 0.125f * 1.44269504f;
  if (idx >= NG) { buf = Kb; i = idx - NG; qsc = 1.0f; }
  int row = i >> 7;
  int g = i & 127;
  int p0 = (g & 7) * 4;
  int col = (g >> 3) * DKH + p0 * 2;
  int s = row & (SEQL - 1);
  float pos = (float)tpos[s];
  size_t o = (size_t)row * D_MODEL + col;
  bf16x8 v = *(bf16x8*)&buf[o];
  bf16x8 out;
  for (int j = 0; j < 4; j++) {
    float freq = exp2f((float)(p0 + j) * (-13.28771238f / 32.0f));
    float ang = pos * freq;
    float sn, cs;
    __sincosf(ang, &sn, &cs);
    cs *= qsc; sn *= qsc;
    float e = (float)v[2 * j], od = (float)v[2 * j + 1];
    out[2 * j]     = (bf16)(e * cs - od * sn);
    out[2 * j + 1] = (bf16)(e * sn + od * cs);
  }
  *(bf16x8*)&buf[o] = out;
}

// ---------------------------------------------------------------------------
// Flash attention, causal, STATIC-MAX (M0): p = exp2(s - M0). No online max,
// no alpha rescale -> contributions are pure sums, combinable by atomicAdd.
// Work unit = (bh, qt, kv-chunk): qt<8 -> 1 chunk (exclusive rows, plain
// stores); qt>=8 -> 2 half-range chunks (atomicAdd into OAcc/lAcc).
// 768 blocks, max 8 kv-iters each, longest-first dispatch.
// Q-tile 128 (wave owns 32 q = 2 m-tiles), KV-tile 128: 64 MFMA/wave/iter.
// LDS: P/Q buf 128*68 + Ks 128*68 + Vt 64*132 (bf16) = 51712 B -> 3 blk/CU.
// ---------------------------------------------------------------------------
#define SM0 24.0f

__global__ __launch_bounds__(256) void attn_kernel(
    const bf16* __restrict__ Q, const bf16* __restrict__ K,
    const bf16* __restrict__ V, float* __restrict__ OAcc,
    float* __restrict__ lAcc) {
  const int t = threadIdx.x;
  const int wave = t >> 6, lane = t & 63;
  const int quad = lane >> 4, l16 = lane & 15;

  const int id = blockIdx.x;
  const int bh = id & 31;
  const int c = 23 - (id >> 5);           // 0..23, longest chunks first
  int qt, k0, k1;
  if (c < 8) {
    qt = c; k0 = 0; k1 = qt;              // exclusive owner of these rows
  } else {
    int e = (c - 8) >> 1;
    qt = 8 + e;
    int n0 = (qt + 2) >> 1;
    if ((c - 8) & 1) { k0 = n0; k1 = qt; } else { k0 = 0; k1 = n0 - 1; }
  }
  const bool exclusive = (qt < 8);
  const int b = bh >> 4, h = bh & 15;
  const int q_base = qt * 128;
  const size_t base = (size_t)b * SEQL * D_MODEL + h * DKH;

  __shared__ bf16 PB[128 * 68];   // Q tile, then per-wave P buffer
  __shared__ bf16 Ks[128 * 68];
  __shared__ bf16 Vt[64 * 132];   // [d][key]

  // stage Q tile (128 x 64)
  for (int i = 0; i < 4; i++) {
    int idx = t + i * 256;
    int row = idx >> 3, c8 = (idx & 7) * 8;
    *(bf16x8*)&PB[row * 68 + c8] =
        *(const bf16x8*)&Q[base + (size_t)(q_base + row) * D_MODEL + c8];
  }
  __syncthreads();

  bf16x8 qa[2][2];
  for (int m = 0; m < 2; m++) {
    int row = wave * 32 + m * 16 + l16;
    qa[m][0] = *(bf16x8*)&PB[row * 68 + quad * 8];
    qa[m][1] = *(bf16x8*)&PB[row * 68 + 32 + quad * 8];
  }

  f32x4 oacc[2][4];
  float l_lane[2][4];
  for (int m = 0; m < 2; m++)
    for (int r = 0; r < 4; r++) {
      l_lane[m][r] = 0.0f;
      for (int dt = 0; dt < 4; dt++) oacc[m][dt][r] = 0.0f;
    }

  const int kp = t & 63;
  const int dgbase = t >> 6;

  for (int kv = k0; kv <= k1; kv++) {
    const int kv_base = kv * 128;
    for (int i = 0; i < 4; i++) {
      int idx = t + i * 256;
      int row = idx >> 3, c8 = (idx & 7) * 8;
      *(bf16x8*)&Ks[row * 68 + c8] =
          *(const bf16x8*)&K[base + (size_t)(kv_base + row) * D_MODEL + c8];
    }
    for (int i = 0; i < 2; i++) {
      int d0 = (dgbase + 4 * i) * 8;
      const bf16* vsrc = &V[base + (size_t)(kv_base + 2 * kp) * D_MODEL + d0];
      bf16x8 g0 = *(const bf16x8*)vsrc;
      bf16x8 g1 = *(const bf16x8*)(vsrc + D_MODEL);
      for (int j = 0; j < 8; j++) {
        bf16x2 w2;
        w2[0] = g0[j];
        w2[1] = g1[j];
        *(bf16x2*)&Vt[(d0 + j) * 132 + 2 * kp] = w2;
      }
    }
    __syncthreads();

    // ---- S = Q K^T : 32 MFMA ----
    f32x4 s[2][8];
    for (int m = 0; m < 2; m++)
      for (int nt = 0; nt < 8; nt++)
        for (int r = 0; r < 4; r++) s[m][nt][r] = 0.0f;
    for (int nt = 0; nt < 8; nt++) {
      bf16x8 kb0 = *(bf16x8*)&Ks[(nt * 16 + l16) * 68 + quad * 8];
      bf16x8 kb1 = *(bf16x8*)&Ks[(nt * 16 + l16) * 68 + 32 + quad * 8];
      for (int m = 0; m < 2; m++) {
        s[m][nt] = mfma16(qa[m][0], kb0, s[m][nt]);
        s[m][nt] = mfma16(qa[m][1], kb1, s[m][nt]);
      }
    }

    // ---- causal mask on the diagonal super-tile ----
    if (kv == qt) {
      for (int m = 0; m < 2; m++) {
        int q0 = wave * 32 + m * 16 + quad * 4;
        for (int nt = 0; nt < 8; nt++) {
          int kc = nt * 16 + l16;
          for (int r = 0; r < 4; r++)
            if (kc > q0 + r) s[m][nt][r] = -1e30f;
        }
      }
    }

    // ---- static-max softmax: p = exp2(s - M0); plain partial sums ----
    for (int m = 0; m < 2; m++) {
      float tsum[4] = {0.f, 0.f, 0.f, 0.f};
      for (int nt = 0; nt < 8; nt++)
        for (int r = 0; r < 4; r++) {
          float p = exp2f(s[m][nt][r] - SM0);
          s[m][nt][r] = p;
          tsum[r] += p;
        }
      for (int r = 0; r < 4; r++) l_lane[m][r] += tsum[r];
    }

    // ---- PV in two 64-key halves through wave-private PB slice ----
    for (int hf = 0; hf < 2; hf++) {
      for (int m = 0; m < 2; m++) {
        int prow = wave * 32 + m * 16 + quad * 4;
        for (int nt = 0; nt < 4; nt++)
          for (int r = 0; r < 4; r++)
            PB[(prow + r) * 68 + nt * 16 + l16] = (bf16)s[m][hf * 4 + nt][r];
      }
      bf16x8 pa[2][2];
      for (int m = 0; m < 2; m++) {
        int row = wave * 32 + m * 16 + l16;
        pa[m][0] = *(bf16x8*)&PB[row * 68 + quad * 8];
        pa[m][1] = *(bf16x8*)&PB[row * 68 + 32 + quad * 8];
      }
      for (int dt = 0; dt < 4; dt++) {
        bf16x8 vb0 = *(bf16x8*)&Vt[(dt * 16 + l16) * 132 + hf * 64 + quad * 8];
        bf16x8 vb1 =
            *(bf16x8*)&Vt[(dt * 16 + l16) * 132 + hf * 64 + 32 + quad * 8];
        for (int m = 0; m < 2; m++) {
          oacc[m][dt] = mfma16(pa[m][0], vb0, oacc[m][dt]);
          oacc[m][dt] = mfma16(pa[m][1], vb1, oacc[m][dt]);
        }
      }
    }
    __syncthreads();
  }

  // ---- l reduce across the 16 key-lanes ----
  float l_full[2][4];
  for (int m = 0; m < 2; m++)
    for (int r = 0; r < 4; r++) l_full[m][r] = l_lane[m][r];
  for (int off = 1; off < 16; off <<= 1)
    for (int m = 0; m < 2; m++)
      for (int r = 0; r < 4; r++)
        l_full[m][r] += __shfl_xor(l_full[m][r], off);

  // ---- write partials: exclusive -> plain store, split -> atomicAdd ----
  for (int m = 0; m < 2; m++) {
    int qrow0 = q_base + wave * 32 + m * 16 + quad * 4;   // + r
    if (l16 == 0) {
      for (int r = 0; r < 4; r++) {
        float* lp = &lAcc[(size_t)(b * SEQL + qrow0 + r) * NHEADS + h];
        if (exclusive) *lp = l_full[m][r];
        else atomicAdd(lp, l_full[m][r]);
      }
    }
    for (int dt = 0; dt < 4; dt++)
      for (int r = 0; r < 4; r++) {
        float* op = &OAcc[(size_t)(b * SEQL + qrow0 + r) * D_MODEL + h * DKH +
                          dt * 16 + l16];
        if (exclusive) *op = oacc[m][dt][r];
        else atomicAdd(op, oacc[m][dt][r]);
      }
  }
}

// ---------------------------------------------------------------------------
// normalize: Cc[r][c] = bf16( OAcc[r][c] / lAcc[r][c/64] )
// ---------------------------------------------------------------------------
__global__ __launch_bounds__(256) void normalize_kernel(
    const float* __restrict__ OAcc, const float* __restrict__ lAcc,
    bf16* __restrict__ Cc) {
  int i4 = blockIdx.x * 256 + threadIdx.x;     // quad of f32
  int row = i4 >> 8;                            // 256 quads per row
  int c0 = (i4 & 255) * 4;
  float inv = 1.0f / lAcc[(size_t)row * NHEADS + (c0 >> 6)];
  f32x4 v = *(const f32x4*)&OAcc[(size_t)row * D_MODEL + c0];
  bf16x4 o;
  o[0] = (bf16)(v[0] * inv);
  o[1] = (bf16)(v[1] * inv);
  o[2] = (bf16)(v[2] * inv);
  o[3] = (bf16)(v[3] * inv);
  *(bf16x4*)&Cc[(size_t)row * D_MODEL + c0] = o;
}

// ---------------------------------------------------------------------------
extern "C" void kernel_launch(void* const* d_in, const int* in_sizes, int n_in,
                              void* d_out, int out_size, void* d_ws,
                              size_t ws_size, hipStream_t stream) {
  const float* x = (const float*)d_in[0];
  const float* wq = (const float*)d_in[1];
  const float* wk = (const float*)d_in[2];
  const float* wv = (const float*)d_in[3];
  const float* wo = (const float*)d_in[4];
  const int* tpos = (const int*)d_in[6];
  float* out = (float*)d_out;

  char* p = (char*)d_ws;
  bf16* xb  = (bf16*)p; p += (size_t)NROWS * D_MODEL * 2;
  bf16* wqb = (bf16*)p; p += (size_t)D_MODEL * D_MODEL * 2;
  bf16* wkb = (bf16*)p; p += (size_t)D_MODEL * D_MODEL * 2;
  bf16* wvb = (bf16*)p; p += (size_t)D_MODEL * D_MODEL * 2;
  bf16* wob = (bf16*)p; p += (size_t)D_MODEL * D_MODEL * 2;
  bf16* Qb  = (bf16*)p; p += (size_t)NROWS * D_MODEL * 2;
  bf16* Kb  = (bf16*)p; p += (size_t)NROWS * D_MODEL * 2;
  bf16* Vb  = (bf16*)p; p += (size_t)NROWS * D_MODEL * 2;
  bf16* Cc  = (bf16*)p; p += (size_t)NROWS * D_MODEL * 2;
  float* OAcc = (float*)p; p += (size_t)NROWS * D_MODEL * 4;  // 16.8 MB
  float* lAcc = (float*)p; p += (size_t)NROWS * NHEADS * 4;   // 256 KB

  convert_kernel<<<8192, 256, 0, stream>>>(x, wq, wk, wv, wo, xb, wqb, wkb,
                                           wvb, wob);
  qkv_gemm<<<dim3(NROWS / 128, D_MODEL / 128, 3), 256, 0, stream>>>(
      xb, wqb, wkb, wvb, Qb, Kb, Vb);
  rope_kernel<<<4096, 256, 0, stream>>>(Qb, Kb, tpos);
  // zero the split-K accumulators (only qt>=8 regions strictly need it, but
  // one big memset is cheap and capture-safe)
  hipMemsetAsync(OAcc, 0, (size_t)NROWS * D_MODEL * 4, stream);
  hipMemsetAsync(lAcc, 0, (size_t)NROWS * NHEADS * 4, stream);
  attn_kernel<<<768, 256, 0, stream>>>(Qb, Kb, Vb, OAcc, lAcc);
  normalize_kernel<<<NROWS * D_MODEL / 1024, 256, 0, stream>>>(OAcc, lAcc, Cc);
  o_gemm<<<dim3(NROWS / 128, D_MODEL / 128), 256, 0, stream>>>(Cc, wob, out);
}